// Round 4
// baseline (826.534 us; speedup 1.0000x reference)
//
#include <hip/hip_runtime.h>
#include <hip/hip_bf16.h>
#include <math.h>

#define BDIM 1024
#define CDIM 100000
#define DDIM 512
#define FB_STRIDE 72    // fallback path LDS stride
#define FS 72           // fast path LDS stride (64 + 8 pad: rows step 4 banks)

typedef float f32x4 __attribute__((ext_vector_type(4)));
typedef short bf16x8 __attribute__((ext_vector_type(8)));

static __device__ __forceinline__ unsigned short f2bf(float f) {
    union { float f; unsigned int u; } v; v.f = f;
    unsigned int r = v.u + 0x7FFFu + ((v.u >> 16) & 1u);  // RNE
    return (unsigned short)(r >> 16);
}

static __device__ __forceinline__ uint4 pack8(const float4 p, const float4 q) {
    union { unsigned short u[8]; uint4 v; } pk;
    pk.u[0] = f2bf(p.x); pk.u[1] = f2bf(p.y); pk.u[2] = f2bf(p.z); pk.u[3] = f2bf(p.w);
    pk.u[4] = f2bf(q.x); pk.u[5] = f2bf(q.y); pk.u[6] = f2bf(q.z); pk.u[7] = f2bf(q.w);
    return pk.v;
}

// --- L2-normalize 512-float rows -> bf16 rows. One wave per row. ---
__global__ void rownorm_bf16_kernel(const float* __restrict__ in,
                                    unsigned short* __restrict__ outp) {
    const int row  = blockIdx.x * 4 + (threadIdx.x >> 6);
    const int lane = threadIdx.x & 63;
    const float* r = in + (size_t)row * DDIM;
    float4 a = *(const float4*)(r + lane * 4);
    float4 b = *(const float4*)(r + 256 + lane * 4);
    float s = a.x*a.x + a.y*a.y + a.z*a.z + a.w*a.w
            + b.x*b.x + b.y*b.y + b.z*b.z + b.w*b.w;
#pragma unroll
    for (int o = 32; o; o >>= 1) s += __shfl_xor(s, o);
    const float sc = 1.0f / fmaxf(sqrtf(s), 1e-12f);
    ushort4 o0, o1;
    o0.x = f2bf(a.x * sc); o0.y = f2bf(a.y * sc); o0.z = f2bf(a.z * sc); o0.w = f2bf(a.w * sc);
    o1.x = f2bf(b.x * sc); o1.y = f2bf(b.y * sc); o1.z = f2bf(b.z * sc); o1.w = f2bf(b.w * sc);
    *(ushort4*)(outp + (size_t)row * DDIM + lane * 4)       = o0;
    *(ushort4*)(outp + (size_t)row * DDIM + 256 + lane * 4) = o1;
}

// --- fallback: per-row 1/||w|| only ---
__global__ void wnorm_kernel(const float* __restrict__ w, float* __restrict__ sw) {
    const int row  = blockIdx.x * 4 + (threadIdx.x >> 6);
    const int lane = threadIdx.x & 63;
    const float* wr = w + (size_t)row * DDIM;
    float4 a = *(const float4*)(wr + lane * 4);
    float4 b = *(const float4*)(wr + 256 + lane * 4);
    float s = a.x*a.x + a.y*a.y + a.z*a.z + a.w*a.w
            + b.x*b.x + b.y*b.y + b.z*b.z + b.w*b.w;
#pragma unroll
    for (int o = 32; o; o >>= 1) s += __shfl_xor(s, o);
    if (lane == 0) sw[row] = 1.0f / fmaxf(sqrtf(s), 1e-12f);
}

// --- per-row margin delta in fp64 accum / fp32 margin math: cond matches the
// fp32 reference regardless of GEMM noise. diff[r] = cond ? cos(acos(c)+M)-c : 0
__global__ void tdiff_kernel(const float* __restrict__ x,
                             const float* __restrict__ w,
                             const int* __restrict__ tgt,
                             float* __restrict__ diff) {
    const int row  = blockIdx.x * 4 + (threadIdx.x >> 6);
    const int lane = threadIdx.x & 63;
    const int tg   = tgt[row];
    const float* xr = x + (size_t)row * DDIM;
    const float* wr = w + (size_t)tg * DDIM;
    double xx = 0.0, ww = 0.0, xw = 0.0;
#pragma unroll
    for (int i = 0; i < 2; ++i) {
        float4 a = *(const float4*)(xr + i * 256 + lane * 4);
        float4 b = *(const float4*)(wr + i * 256 + lane * 4);
        xx += (double)a.x*a.x + (double)a.y*a.y + (double)a.z*a.z + (double)a.w*a.w;
        ww += (double)b.x*b.x + (double)b.y*b.y + (double)b.z*b.z + (double)b.w*b.w;
        xw += (double)a.x*b.x + (double)a.y*b.y + (double)a.z*b.z + (double)a.w*b.w;
    }
#pragma unroll
    for (int o = 32; o; o >>= 1) {
        xx += __shfl_xor(xx, o);
        ww += __shfl_xor(ww, o);
        xw += __shfl_xor(xw, o);
    }
    if (lane == 0) {
        float nx = fmaxf((float)sqrt(xx), 1e-12f);
        float nw = fmaxf((float)sqrt(ww), 1e-12f);
        float cos_t = (float)xw / (nx * nw);
        float d = 0.0f;
        if (cos_t > 0.0f) {
            float cv = fminf(fmaxf(cos_t, -1.0f), 1.0f);
            d = cv * 0.87758256189037276f
              - sqrtf(fmaxf(0.0f, 1.0f - cv * cv)) * 0.47942553860420301f
              - cos_t;
        }
        diff[row] = d;
    }
}

// =====================  FAST PATH (reg-staged, no async DMA)  =====================
// All-bf16 GEMM: 128x128 tile, BK=64, SINGLE padded LDS buffer (36.9 KB -> 4
// blocks/CU), global->reg prefetch of tile t+1 issued under tile t's MFMAs,
// 2 barriers per K-step. Sync structure == round-1's verified-pass kernel:
// only compiler-tracked ds_read/ds_write/global_load (no vmcnt DMA hazards).
__global__ __launch_bounds__(256, 3)
void arc_gemm_fast(const unsigned short* __restrict__ xn,
                   const unsigned short* __restrict__ wn,
                   const int* __restrict__ tgt,
                   const float* __restrict__ diff,
                   float* __restrict__ out) {
    __shared__ unsigned short As[128 * FS];
    __shared__ unsigned short Bs[128 * FS];

    const int t    = threadIdx.x;
    const int lane = t & 63;
    const int wid  = t >> 6;

    // XCD-chunked bijection: 6256 blocks = 8 XCDs x 782; consecutive logical
    // ids (m-inner, sharing one weight tile) land on the SAME XCD's L2.
    const int logical = (blockIdx.x & 7) * 782 + (blockIdx.x >> 3);
    const int mt = logical & 7;
    const int nt = logical >> 3;
    const int m0 = mt * 128;
    const int n0 = nt * 128;
    const int wm = (wid & 1) * 64;
    const int wnc = (wid >> 1) * 64;

    // staging: 2 threads per row, 32 k-elems (4x uint4) each
    const int sr = t >> 1;
    const int sk = (t & 1) * 32;
    const unsigned short* Ag = xn + (size_t)(m0 + sr) * DDIM + sk;
    int brow = n0 + sr; brow = brow < CDIM ? brow : (CDIM - 1);   // tail clamp
    const unsigned short* Bg = wn + (size_t)brow * DDIM + sk;
    unsigned short* al = &As[sr * FS + sk];
    unsigned short* bl = &Bs[sr * FS + sk];

    f32x4 acc[4][4] = {};
    uint4 ar[4], br[4];

#pragma unroll
    for (int i = 0; i < 4; ++i) {           // prologue: tile 0 -> regs
        ar[i] = *(const uint4*)(Ag + i * 8);
        br[i] = *(const uint4*)(Bg + i * 8);
    }

#pragma unroll
    for (int ks = 0; ks < 8; ++ks) {
#pragma unroll
        for (int i = 0; i < 4; ++i) {       // regs -> LDS
            *(uint4*)(al + i * 8) = ar[i];
            *(uint4*)(bl + i * 8) = br[i];
        }
        __syncthreads();                    // writes visible to all waves
        if (ks < 7) {
#pragma unroll
            for (int i = 0; i < 4; ++i) {   // prefetch tile ks+1 (used after next barrier)
                ar[i] = *(const uint4*)(Ag + (ks + 1) * 64 + i * 8);
                br[i] = *(const uint4*)(Bg + (ks + 1) * 64 + i * 8);
            }
        }
#pragma unroll
        for (int hk = 0; hk < 2; ++hk) {
            bf16x8 av[4], bv[4];
            const int ko = hk * 32 + (lane >> 4) * 8;
#pragma unroll
            for (int f = 0; f < 4; ++f) {
                av[f] = *(const bf16x8*)(&As[(wm  + f * 16 + (lane & 15)) * FS + ko]);
                bv[f] = *(const bf16x8*)(&Bs[(wnc + f * 16 + (lane & 15)) * FS + ko]);
            }
#pragma unroll
            for (int mf = 0; mf < 4; ++mf)
#pragma unroll
                for (int nf = 0; nf < 4; ++nf)
                    acc[mf][nf] = __builtin_amdgcn_mfma_f32_16x16x32_bf16(
                        av[mf], bv[nf], acc[mf][nf], 0, 0, 0);
        }
        if (ks < 7) __syncthreads();        // all reads done before next overwrite
    }

    // epilogue: add precomputed margin delta at target col, * S, tail-predicated
    int gcv[4];
#pragma unroll
    for (int nf = 0; nf < 4; ++nf) gcv[nf] = n0 + wnc + nf * 16 + (lane & 15);
#pragma unroll
    for (int mf = 0; mf < 4; ++mf) {
#pragma unroll
        for (int j = 0; j < 4; ++j) {
            const int grow = m0 + wm + mf * 16 + (lane >> 4) * 4 + j;
            const int tg = tgt[grow];
            const float dv = diff[grow];
            float* orow = out + (size_t)grow * CDIM;
#pragma unroll
            for (int nf = 0; nf < 4; ++nf) {
                const int gc = gcv[nf];
                if (gc < CDIM) {
                    float v = acc[mf][nf][j];
                    if (gc == tg) v += dv;
                    orow[gc] = v * 64.0f;
                }
            }
        }
    }
}

// =====================  FALLBACK PATH (round-1 structure, fp32 B)  =====================
__global__ __launch_bounds__(256, 2)
void arc_gemm_kernel(const unsigned short* __restrict__ xn,
                     const float* __restrict__ w,
                     const float* __restrict__ sw,
                     const int* __restrict__ tgt,
                     const float* __restrict__ diff,
                     float* __restrict__ out) {
    __shared__ unsigned short As[2][128 * FB_STRIDE];
    __shared__ unsigned short Bs[2][128 * FB_STRIDE];

    const int t    = threadIdx.x;
    const int lane = t & 63;
    const int wid  = t >> 6;
    const int mt   = blockIdx.x & 7;
    const int nt   = blockIdx.x >> 3;
    const int m0   = mt * 128;
    const int n0   = nt * 128;
    const int wm   = (wid & 1) * 64;
    const int wn   = (wid >> 1) * 64;

    const int sr = t >> 1;
    const int sk = (t & 1) * 32;

    const unsigned short* Ag = xn + (m0 + sr) * DDIM + sk;
    int brow = n0 + sr; brow = brow < CDIM ? brow : (CDIM - 1);
    const float* Bg = w + (size_t)brow * DDIM + sk;

    f32x4 acc[4][4] = {};
    uint4  ar[4];
    float4 br[8];

#define LOAD_TILE(kk) do {                                                     \
    _Pragma("unroll") for (int i = 0; i < 4; ++i)                              \
        ar[i] = *(const uint4*)(Ag + (kk) + i * 8);                            \
    _Pragma("unroll") for (int i = 0; i < 8; ++i)                              \
        br[i] = *(const float4*)(Bg + (kk) + i * 4);                           \
} while (0)

#define STORE_TILE(bufi) do {                                                  \
    unsigned short* ab = &As[bufi][sr * FB_STRIDE + sk];                       \
    unsigned short* bb = &Bs[bufi][sr * FB_STRIDE + sk];                       \
    _Pragma("unroll") for (int i = 0; i < 4; ++i)                              \
        *(uint4*)(ab + i * 8) = ar[i];                                         \
    _Pragma("unroll") for (int j = 0; j < 4; ++j)                              \
        *(uint4*)(bb + j * 8) = pack8(br[2 * j], br[2 * j + 1]);               \
} while (0)

#define MFMA_STEP(bufi) do {                                                   \
    _Pragma("unroll") for (int hk = 0; hk < 2; ++hk) {                         \
        bf16x8 av[4], bv[4];                                                   \
        const int ko = hk * 32 + (lane >> 4) * 8;                              \
        _Pragma("unroll") for (int f = 0; f < 4; ++f) {                        \
            av[f] = *(const bf16x8*)(&As[bufi][(wm + f * 16 + (lane & 15)) * FB_STRIDE + ko]); \
            bv[f] = *(const bf16x8*)(&Bs[bufi][(wn + f * 16 + (lane & 15)) * FB_STRIDE + ko]); \
        }                                                                      \
        _Pragma("unroll") for (int mf = 0; mf < 4; ++mf)                       \
            _Pragma("unroll") for (int nf = 0; nf < 4; ++nf)                   \
                acc[mf][nf] = __builtin_amdgcn_mfma_f32_16x16x32_bf16(         \
                    av[mf], bv[nf], acc[mf][nf], 0, 0, 0);                     \
    }                                                                          \
} while (0)

    LOAD_TILE(0);
    STORE_TILE(0);
#pragma unroll
    for (int ks = 0; ks < 8; ++ks) {
        const int cur = ks & 1;
        if (ks < 7) LOAD_TILE((ks + 1) * 64);
        __syncthreads();
        MFMA_STEP(cur);
        if (ks < 7) STORE_TILE(cur ^ 1);
    }

    float swv[4];
    int   gcv[4];
#pragma unroll
    for (int nf = 0; nf < 4; ++nf) {
        int gc = n0 + wn + nf * 16 + (lane & 15);
        gcv[nf] = gc;
        swv[nf] = sw[gc < CDIM ? gc : (CDIM - 1)];
    }
#pragma unroll
    for (int mf = 0; mf < 4; ++mf) {
#pragma unroll
        for (int j = 0; j < 4; ++j) {
            const int grow = m0 + wm + mf * 16 + (lane >> 4) * 4 + j;
            const int tg = tgt[grow];
            const float dv = diff[grow];
            float* orow = out + (size_t)grow * CDIM;
#pragma unroll
            for (int nf = 0; nf < 4; ++nf) {
                const int gc = gcv[nf];
                if (gc < CDIM) {
                    float v = acc[mf][nf][j] * swv[nf];
                    if (gc == tg) v += dv;
                    orow[gc] = v * 64.0f;
                }
            }
        }
    }
#undef LOAD_TILE
#undef STORE_TILE
#undef MFMA_STEP
}

extern "C" void kernel_launch(void* const* d_in, const int* in_sizes, int n_in,
                              void* d_out, int out_size, void* d_ws, size_t ws_size,
                              hipStream_t stream) {
    const float* x   = (const float*)d_in[0];
    const float* w   = (const float*)d_in[1];
    const int*   tgt = (const int*)d_in[2];
    float* out = (float*)d_out;

    unsigned short* xn = (unsigned short*)d_ws;                          // 1 MB
    const size_t xn_bytes   = (size_t)BDIM * DDIM * 2;
    float* diff = (float*)((char*)d_ws + xn_bytes);                      // 4 KB
    const size_t diff_bytes = (size_t)BDIM * 4;
    const size_t wn_bytes   = (size_t)CDIM * DDIM * 2;                   // 102.4 MB
    const int ntiles = (CDIM + 127) / 128;                               // 782

    hipLaunchKernelGGL(rownorm_bf16_kernel, dim3(BDIM / 4), dim3(256), 0, stream, x, xn);
    hipLaunchKernelGGL(tdiff_kernel, dim3(BDIM / 4), dim3(256), 0, stream, x, w, tgt, diff);

    if (ws_size >= xn_bytes + diff_bytes + wn_bytes) {
        // FAST: normalize+convert weight once, then all-bf16 reg-staged GEMM
        unsigned short* wnb = (unsigned short*)((char*)d_ws + xn_bytes + diff_bytes);
        hipLaunchKernelGGL(rownorm_bf16_kernel, dim3(CDIM / 4), dim3(256), 0, stream, w, wnb);
        hipLaunchKernelGGL(arc_gemm_fast, dim3(8 * ntiles), dim3(256), 0, stream,
                           xn, wnb, tgt, diff, out);
    } else {
        // FALLBACK: fp32 B, reg-staged, round-1-verified structure
        float* sw = (float*)((char*)d_ws + xn_bytes + diff_bytes);
        hipLaunchKernelGGL(wnorm_kernel, dim3(CDIM / 4), dim3(256), 0, stream, w, sw);
        hipLaunchKernelGGL(arc_gemm_kernel, dim3(8 * ntiles), dim3(256), 0, stream,
                           xn, w, sw, tgt, diff, out);
    }
}

// Round 5
// 784.580 us; speedup vs baseline: 1.0535x; 1.0535x over previous
//
#include <hip/hip_runtime.h>
#include <hip/hip_bf16.h>
#include <math.h>

#define BDIM 1024
#define CDIM 100000
#define DDIM 512
#define FB_STRIDE 72    // fallback path LDS stride
#define FS 72           // fast path LDS stride (64 + 8 pad)

typedef float f32x4 __attribute__((ext_vector_type(4)));
typedef short bf16x8 __attribute__((ext_vector_type(8)));

static __device__ __forceinline__ unsigned short f2bf(float f) {
    union { float f; unsigned int u; } v; v.f = f;
    unsigned int r = v.u + 0x7FFFu + ((v.u >> 16) & 1u);  // RNE
    return (unsigned short)(r >> 16);
}

static __device__ __forceinline__ uint4 pack8(const float4 p, const float4 q) {
    union { unsigned short u[8]; uint4 v; } pk;
    pk.u[0] = f2bf(p.x); pk.u[1] = f2bf(p.y); pk.u[2] = f2bf(p.z); pk.u[3] = f2bf(p.w);
    pk.u[4] = f2bf(q.x); pk.u[5] = f2bf(q.y); pk.u[6] = f2bf(q.z); pk.u[7] = f2bf(q.w);
    return pk.v;
}

// --- L2-normalize 512-float rows -> bf16 rows. One wave per row. ---
__global__ void rownorm_bf16_kernel(const float* __restrict__ in,
                                    unsigned short* __restrict__ outp) {
    const int row  = blockIdx.x * 4 + (threadIdx.x >> 6);
    const int lane = threadIdx.x & 63;
    const float* r = in + (size_t)row * DDIM;
    float4 a = *(const float4*)(r + lane * 4);
    float4 b = *(const float4*)(r + 256 + lane * 4);
    float s = a.x*a.x + a.y*a.y + a.z*a.z + a.w*a.w
            + b.x*b.x + b.y*b.y + b.z*b.z + b.w*b.w;
#pragma unroll
    for (int o = 32; o; o >>= 1) s += __shfl_xor(s, o);
    const float sc = 1.0f / fmaxf(sqrtf(s), 1e-12f);
    ushort4 o0, o1;
    o0.x = f2bf(a.x * sc); o0.y = f2bf(a.y * sc); o0.z = f2bf(a.z * sc); o0.w = f2bf(a.w * sc);
    o1.x = f2bf(b.x * sc); o1.y = f2bf(b.y * sc); o1.z = f2bf(b.z * sc); o1.w = f2bf(b.w * sc);
    *(ushort4*)(outp + (size_t)row * DDIM + lane * 4)       = o0;
    *(ushort4*)(outp + (size_t)row * DDIM + 256 + lane * 4) = o1;
}

// --- fallback: per-row 1/||w|| only ---
__global__ void wnorm_kernel(const float* __restrict__ w, float* __restrict__ sw) {
    const int row  = blockIdx.x * 4 + (threadIdx.x >> 6);
    const int lane = threadIdx.x & 63;
    const float* wr = w + (size_t)row * DDIM;
    float4 a = *(const float4*)(wr + lane * 4);
    float4 b = *(const float4*)(wr + 256 + lane * 4);
    float s = a.x*a.x + a.y*a.y + a.z*a.z + a.w*a.w
            + b.x*b.x + b.y*b.y + b.z*b.z + b.w*b.w;
#pragma unroll
    for (int o = 32; o; o >>= 1) s += __shfl_xor(s, o);
    if (lane == 0) sw[row] = 1.0f / fmaxf(sqrtf(s), 1e-12f);
}

// --- per-row margin delta in fp64 accum / fp32 margin math: cond matches the
// fp32 reference regardless of GEMM noise. diff[r] = cond ? cos(acos(c)+M)-c : 0
__global__ void tdiff_kernel(const float* __restrict__ x,
                             const float* __restrict__ w,
                             const int* __restrict__ tgt,
                             float* __restrict__ diff) {
    const int row  = blockIdx.x * 4 + (threadIdx.x >> 6);
    const int lane = threadIdx.x & 63;
    const int tg   = tgt[row];
    const float* xr = x + (size_t)row * DDIM;
    const float* wr = w + (size_t)tg * DDIM;
    double xx = 0.0, ww = 0.0, xw = 0.0;
#pragma unroll
    for (int i = 0; i < 2; ++i) {
        float4 a = *(const float4*)(xr + i * 256 + lane * 4);
        float4 b = *(const float4*)(wr + i * 256 + lane * 4);
        xx += (double)a.x*a.x + (double)a.y*a.y + (double)a.z*a.z + (double)a.w*a.w;
        ww += (double)b.x*b.x + (double)b.y*b.y + (double)b.z*b.z + (double)b.w*b.w;
        xw += (double)a.x*b.x + (double)a.y*b.y + (double)a.z*b.z + (double)a.w*b.w;
    }
#pragma unroll
    for (int o = 32; o; o >>= 1) {
        xx += __shfl_xor(xx, o);
        ww += __shfl_xor(ww, o);
        xw += __shfl_xor(xw, o);
    }
    if (lane == 0) {
        float nx = fmaxf((float)sqrt(xx), 1e-12f);
        float nw = fmaxf((float)sqrt(ww), 1e-12f);
        float cos_t = (float)xw / (nx * nw);
        float d = 0.0f;
        if (cos_t > 0.0f) {
            float cv = fminf(fmaxf(cos_t, -1.0f), 1.0f);
            d = cv * 0.87758256189037276f
              - sqrtf(fmaxf(0.0f, 1.0f - cv * cv)) * 0.47942553860420301f
              - cos_t;
        }
        diff[row] = d;
    }
}

// =====================  FAST PATH (reg-staged, no async DMA)  =====================
// All-bf16 GEMM: 128x128 tile, BK=64, SINGLE padded LDS buffer, global->reg
// prefetch under MFMAs, 2 barriers/K-step (round-4-verified sync structure).
// NEW: full-line float4 epilogue via LDS re-staging — the round-4 counters
// showed 4.8x HBM write amplification (2 GB written for a 410 MB output) from
// 64B partial-line store segments; this epilogue emits only dense 512B row
// segments so L2 retires full lines once.
__global__ __launch_bounds__(256, 4)
void arc_gemm_fast(const unsigned short* __restrict__ xn,
                   const unsigned short* __restrict__ wn,
                   const int* __restrict__ tgt,
                   const float* __restrict__ diff,
                   float* __restrict__ out) {
    __shared__ unsigned short SMEM[2 * 128 * FS];   // As | Bs; reused as float[64][128]
    unsigned short* const As = SMEM;
    unsigned short* const Bs = SMEM + 128 * FS;

    const int t    = threadIdx.x;
    const int lane = t & 63;
    const int wid  = t >> 6;

    // XCD-chunked bijection: 6256 blocks = 8 XCDs x 782; consecutive logical
    // ids (m-inner, sharing one weight tile) land on the SAME XCD's L2.
    const int logical = (blockIdx.x & 7) * 782 + (blockIdx.x >> 3);
    const int mt = logical & 7;
    const int nt = logical >> 3;
    const int m0 = mt * 128;
    const int n0 = nt * 128;
    const int wm = (wid & 1) * 64;
    const int wnc = (wid >> 1) * 64;

    // staging: 2 threads per row, 32 k-elems (4x uint4) each
    const int sr = t >> 1;
    const int sk = (t & 1) * 32;
    const unsigned short* Ag = xn + (size_t)(m0 + sr) * DDIM + sk;
    int brow = n0 + sr; brow = brow < CDIM ? brow : (CDIM - 1);   // tail clamp
    const unsigned short* Bg = wn + (size_t)brow * DDIM + sk;
    unsigned short* al = &As[sr * FS + sk];
    unsigned short* bl = &Bs[sr * FS + sk];

    f32x4 acc[4][4] = {};
    uint4 ar[4], br[4];

#pragma unroll
    for (int i = 0; i < 4; ++i) {           // prologue: tile 0 -> regs
        ar[i] = *(const uint4*)(Ag + i * 8);
        br[i] = *(const uint4*)(Bg + i * 8);
    }

#pragma unroll
    for (int ks = 0; ks < 8; ++ks) {
#pragma unroll
        for (int i = 0; i < 4; ++i) {       // regs -> LDS
            *(uint4*)(al + i * 8) = ar[i];
            *(uint4*)(bl + i * 8) = br[i];
        }
        __syncthreads();                    // writes visible to all waves
        if (ks < 7) {
#pragma unroll
            for (int i = 0; i < 4; ++i) {   // prefetch tile ks+1 (used after next barrier)
                ar[i] = *(const uint4*)(Ag + (ks + 1) * 64 + i * 8);
                br[i] = *(const uint4*)(Bg + (ks + 1) * 64 + i * 8);
            }
        }
#pragma unroll
        for (int hk = 0; hk < 2; ++hk) {
            bf16x8 av[4], bv[4];
            const int ko = hk * 32 + (lane >> 4) * 8;
#pragma unroll
            for (int f = 0; f < 4; ++f) {
                av[f] = *(const bf16x8*)(&As[(wm  + f * 16 + (lane & 15)) * FS + ko]);
                bv[f] = *(const bf16x8*)(&Bs[(wnc + f * 16 + (lane & 15)) * FS + ko]);
            }
#pragma unroll
            for (int mf = 0; mf < 4; ++mf)
#pragma unroll
                for (int nf = 0; nf < 4; ++nf)
                    acc[mf][nf] = __builtin_amdgcn_mfma_f32_16x16x32_bf16(
                        av[mf], bv[nf], acc[mf][nf], 0, 0, 0);
        }
        if (ks < 7) __syncthreads();        // all reads done before next overwrite
    }

    // ---- full-line epilogue: 2 passes of 64 rows through LDS ----
    float* const Cs = (float*)SMEM;         // [64][128] fp32 = 32 KB
#pragma unroll
    for (int p = 0; p < 2; ++p) {
        __syncthreads();                    // LDS free (prev MFMA reads / prev store pass done)
        if ((wid & 1) == p) {               // waves holding rows [p*64, p*64+64)
#pragma unroll
            for (int mf = 0; mf < 4; ++mf)
#pragma unroll
                for (int j = 0; j < 4; ++j) {
                    const int lr = mf * 16 + (lane >> 4) * 4 + j;
#pragma unroll
                    for (int nf = 0; nf < 4; ++nf)
                        Cs[lr * 128 + wnc + nf * 16 + (lane & 15)] = acc[mf][nf][j];
                }
        }
        __syncthreads();
        // 256 threads: 8 rows/iter, 32 float4 per row (dense 512B row segments)
#pragma unroll
        for (int it = 0; it < 8; ++it) {
            const int r    = it * 8 + (t >> 5);     // 0..63
            const int c4   = (t & 31) * 4;          // col within tile
            const int grow = m0 + p * 64 + r;
            const int gc0  = n0 + c4;
            if (gc0 < CDIM) {
                float4 v = *(const float4*)&Cs[r * 128 + c4];
                const int   tg = tgt[grow];
                const float dv = diff[grow];
                if (gc0     == tg) v.x += dv;
                if (gc0 + 1 == tg) v.y += dv;
                if (gc0 + 2 == tg) v.z += dv;
                if (gc0 + 3 == tg) v.w += dv;
                v.x *= 64.0f; v.y *= 64.0f; v.z *= 64.0f; v.w *= 64.0f;
                *(float4*)(out + (size_t)grow * CDIM + gc0) = v;
            }
        }
    }
}

// =====================  FALLBACK PATH (round-1 structure, fp32 B)  =====================
__global__ __launch_bounds__(256, 2)
void arc_gemm_kernel(const unsigned short* __restrict__ xn,
                     const float* __restrict__ w,
                     const float* __restrict__ sw,
                     const int* __restrict__ tgt,
                     const float* __restrict__ diff,
                     float* __restrict__ out) {
    __shared__ unsigned short As[2][128 * FB_STRIDE];
    __shared__ unsigned short Bs[2][128 * FB_STRIDE];

    const int t    = threadIdx.x;
    const int lane = t & 63;
    const int wid  = t >> 6;
    const int mt   = blockIdx.x & 7;
    const int nt   = blockIdx.x >> 3;
    const int m0   = mt * 128;
    const int n0   = nt * 128;
    const int wm   = (wid & 1) * 64;
    const int wn   = (wid >> 1) * 64;

    const int sr = t >> 1;
    const int sk = (t & 1) * 32;

    const unsigned short* Ag = xn + (m0 + sr) * DDIM + sk;
    int brow = n0 + sr; brow = brow < CDIM ? brow : (CDIM - 1);
    const float* Bg = w + (size_t)brow * DDIM + sk;

    f32x4 acc[4][4] = {};
    uint4  ar[4];
    float4 br[8];

#define LOAD_TILE(kk) do {                                                     \
    _Pragma("unroll") for (int i = 0; i < 4; ++i)                              \
        ar[i] = *(const uint4*)(Ag + (kk) + i * 8);                            \
    _Pragma("unroll") for (int i = 0; i < 8; ++i)                              \
        br[i] = *(const float4*)(Bg + (kk) + i * 4);                           \
} while (0)

#define STORE_TILE(bufi) do {                                                  \
    unsigned short* ab = &As[bufi][sr * FB_STRIDE + sk];                       \
    unsigned short* bb = &Bs[bufi][sr * FB_STRIDE + sk];                       \
    _Pragma("unroll") for (int i = 0; i < 4; ++i)                              \
        *(uint4*)(ab + i * 8) = ar[i];                                         \
    _Pragma("unroll") for (int j = 0; j < 4; ++j)                              \
        *(uint4*)(bb + j * 8) = pack8(br[2 * j], br[2 * j + 1]);               \
} while (0)

#define MFMA_STEP(bufi) do {                                                   \
    _Pragma("unroll") for (int hk = 0; hk < 2; ++hk) {                         \
        bf16x8 av[4], bv[4];                                                   \
        const int ko = hk * 32 + (lane >> 4) * 8;                              \
        _Pragma("unroll") for (int f = 0; f < 4; ++f) {                        \
            av[f] = *(const bf16x8*)(&As[bufi][(wm + f * 16 + (lane & 15)) * FB_STRIDE + ko]); \
            bv[f] = *(const bf16x8*)(&Bs[bufi][(wn + f * 16 + (lane & 15)) * FB_STRIDE + ko]); \
        }                                                                      \
        _Pragma("unroll") for (int mf = 0; mf < 4; ++mf)                       \
            _Pragma("unroll") for (int nf = 0; nf < 4; ++nf)                   \
                acc[mf][nf] = __builtin_amdgcn_mfma_f32_16x16x32_bf16(         \
                    av[mf], bv[nf], acc[mf][nf], 0, 0, 0);                     \
    }                                                                          \
} while (0)

    LOAD_TILE(0);
    STORE_TILE(0);
#pragma unroll
    for (int ks = 0; ks < 8; ++ks) {
        const int cur = ks & 1;
        if (ks < 7) LOAD_TILE((ks + 1) * 64);
        __syncthreads();
        MFMA_STEP(cur);
        if (ks < 7) STORE_TILE(cur ^ 1);
    }

    float swv[4];
    int   gcv[4];
#pragma unroll
    for (int nf = 0; nf < 4; ++nf) {
        int gc = n0 + wn + nf * 16 + (lane & 15);
        gcv[nf] = gc;
        swv[nf] = sw[gc < CDIM ? gc : (CDIM - 1)];
    }
#pragma unroll
    for (int mf = 0; mf < 4; ++mf) {
#pragma unroll
        for (int j = 0; j < 4; ++j) {
            const int grow = m0 + wm + mf * 16 + (lane >> 4) * 4 + j;
            const int tg = tgt[grow];
            const float dv = diff[grow];
            float* orow = out + (size_t)grow * CDIM;
#pragma unroll
            for (int nf = 0; nf < 4; ++nf) {
                const int gc = gcv[nf];
                if (gc < CDIM) {
                    float v = acc[mf][nf][j] * swv[nf];
                    if (gc == tg) v += dv;
                    orow[gc] = v * 64.0f;
                }
            }
        }
    }
#undef LOAD_TILE
#undef STORE_TILE
#undef MFMA_STEP
}

extern "C" void kernel_launch(void* const* d_in, const int* in_sizes, int n_in,
                              void* d_out, int out_size, void* d_ws, size_t ws_size,
                              hipStream_t stream) {
    const float* x   = (const float*)d_in[0];
    const float* w   = (const float*)d_in[1];
    const int*   tgt = (const int*)d_in[2];
    float* out = (float*)d_out;

    unsigned short* xn = (unsigned short*)d_ws;                          // 1 MB
    const size_t xn_bytes   = (size_t)BDIM * DDIM * 2;
    float* diff = (float*)((char*)d_ws + xn_bytes);                      // 4 KB
    const size_t diff_bytes = (size_t)BDIM * 4;
    const size_t wn_bytes   = (size_t)CDIM * DDIM * 2;                   // 102.4 MB
    const int ntiles = (CDIM + 127) / 128;                               // 782

    hipLaunchKernelGGL(rownorm_bf16_kernel, dim3(BDIM / 4), dim3(256), 0, stream, x, xn);
    hipLaunchKernelGGL(tdiff_kernel, dim3(BDIM / 4), dim3(256), 0, stream, x, w, tgt, diff);

    if (ws_size >= xn_bytes + diff_bytes + wn_bytes) {
        // FAST: normalize+convert weight once, then all-bf16 reg-staged GEMM
        unsigned short* wnb = (unsigned short*)((char*)d_ws + xn_bytes + diff_bytes);
        hipLaunchKernelGGL(rownorm_bf16_kernel, dim3(CDIM / 4), dim3(256), 0, stream, w, wnb);
        hipLaunchKernelGGL(arc_gemm_fast, dim3(8 * ntiles), dim3(256), 0, stream,
                           xn, wnb, tgt, diff, out);
    } else {
        // FALLBACK: fp32 B, reg-staged, round-1-verified structure
        float* sw = (float*)((char*)d_ws + xn_bytes + diff_bytes);
        hipLaunchKernelGGL(wnorm_kernel, dim3(CDIM / 4), dim3(256), 0, stream, w, sw);
        hipLaunchKernelGGL(arc_gemm_kernel, dim3(8 * ntiles), dim3(256), 0, stream,
                           xn, w, sw, tgt, diff, out);
    }
}

// Round 7
// 724.186 us; speedup vs baseline: 1.1413x; 1.0834x over previous
//
#include <hip/hip_runtime.h>
#include <hip/hip_bf16.h>
#include <math.h>

#define BDIM 1024
#define CDIM 100000
#define DDIM 512
#define FB_STRIDE 72    // fallback path LDS stride
#define FS 72           // fast path LDS stride (64 + 8 pad)

typedef float f32x4 __attribute__((ext_vector_type(4)));
typedef short bf16x8 __attribute__((ext_vector_type(8)));

static __device__ __forceinline__ unsigned short f2bf(float f) {
    union { float f; unsigned int u; } v; v.f = f;
    unsigned int r = v.u + 0x7FFFu + ((v.u >> 16) & 1u);  // RNE
    return (unsigned short)(r >> 16);
}

static __device__ __forceinline__ uint4 pack8(const float4 p, const float4 q) {
    union { unsigned short u[8]; uint4 v; } pk;
    pk.u[0] = f2bf(p.x); pk.u[1] = f2bf(p.y); pk.u[2] = f2bf(p.z); pk.u[3] = f2bf(p.w);
    pk.u[4] = f2bf(q.x); pk.u[5] = f2bf(q.y); pk.u[6] = f2bf(q.z); pk.u[7] = f2bf(q.w);
    return pk.v;
}

// --- L2-normalize 512-float rows -> bf16 rows. One wave per row. ---
__global__ void rownorm_bf16_kernel(const float* __restrict__ in,
                                    unsigned short* __restrict__ outp) {
    const int row  = blockIdx.x * 4 + (threadIdx.x >> 6);
    const int lane = threadIdx.x & 63;
    const float* r = in + (size_t)row * DDIM;
    float4 a = *(const float4*)(r + lane * 4);
    float4 b = *(const float4*)(r + 256 + lane * 4);
    float s = a.x*a.x + a.y*a.y + a.z*a.z + a.w*a.w
            + b.x*b.x + b.y*b.y + b.z*b.z + b.w*b.w;
#pragma unroll
    for (int o = 32; o; o >>= 1) s += __shfl_xor(s, o);
    const float sc = 1.0f / fmaxf(sqrtf(s), 1e-12f);
    ushort4 o0, o1;
    o0.x = f2bf(a.x * sc); o0.y = f2bf(a.y * sc); o0.z = f2bf(a.z * sc); o0.w = f2bf(a.w * sc);
    o1.x = f2bf(b.x * sc); o1.y = f2bf(b.y * sc); o1.z = f2bf(b.z * sc); o1.w = f2bf(b.w * sc);
    *(ushort4*)(outp + (size_t)row * DDIM + lane * 4)       = o0;
    *(ushort4*)(outp + (size_t)row * DDIM + 256 + lane * 4) = o1;
}

// --- fallback: per-row 1/||w|| only ---
__global__ void wnorm_kernel(const float* __restrict__ w, float* __restrict__ sw) {
    const int row  = blockIdx.x * 4 + (threadIdx.x >> 6);
    const int lane = threadIdx.x & 63;
    const float* wr = w + (size_t)row * DDIM;
    float4 a = *(const float4*)(wr + lane * 4);
    float4 b = *(const float4*)(wr + 256 + lane * 4);
    float s = a.x*a.x + a.y*a.y + a.z*a.z + a.w*a.w
            + b.x*b.x + b.y*b.y + b.z*b.z + b.w*b.w;
#pragma unroll
    for (int o = 32; o; o >>= 1) s += __shfl_xor(s, o);
    if (lane == 0) sw[row] = 1.0f / fmaxf(sqrtf(s), 1e-12f);
}

// --- per-row margin delta in fp64 accum / fp32 margin math: cond matches the
// fp32 reference regardless of GEMM noise. diff[r] = cond ? cos(acos(c)+M)-c : 0
__global__ void tdiff_kernel(const float* __restrict__ x,
                             const float* __restrict__ w,
                             const int* __restrict__ tgt,
                             float* __restrict__ diff) {
    const int row  = blockIdx.x * 4 + (threadIdx.x >> 6);
    const int lane = threadIdx.x & 63;
    const int tg   = tgt[row];
    const float* xr = x + (size_t)row * DDIM;
    const float* wr = w + (size_t)tg * DDIM;
    double xx = 0.0, ww = 0.0, xw = 0.0;
#pragma unroll
    for (int i = 0; i < 2; ++i) {
        float4 a = *(const float4*)(xr + i * 256 + lane * 4);
        float4 b = *(const float4*)(wr + i * 256 + lane * 4);
        xx += (double)a.x*a.x + (double)a.y*a.y + (double)a.z*a.z + (double)a.w*a.w;
        ww += (double)b.x*b.x + (double)b.y*b.y + (double)b.z*b.z + (double)b.w*b.w;
        xw += (double)a.x*b.x + (double)a.y*b.y + (double)a.z*b.z + (double)a.w*b.w;
    }
#pragma unroll
    for (int o = 32; o; o >>= 1) {
        xx += __shfl_xor(xx, o);
        ww += __shfl_xor(ww, o);
        xw += __shfl_xor(xw, o);
    }
    if (lane == 0) {
        float nx = fmaxf((float)sqrt(xx), 1e-12f);
        float nw = fmaxf((float)sqrt(ww), 1e-12f);
        float cos_t = (float)xw / (nx * nw);
        float d = 0.0f;
        if (cos_t > 0.0f) {
            float cv = fminf(fmaxf(cos_t, -1.0f), 1.0f);
            d = cv * 0.87758256189037276f
              - sqrtf(fmaxf(0.0f, 1.0f - cv * cv)) * 0.47942553860420301f
              - cos_t;
        }
        diff[row] = d;
    }
}

// =====================  FAST PATH  =====================
// All-bf16 GEMM: 128x128 tile, BK=64, SINGLE padded LDS buffer (4 blocks/CU),
// TWO-tile-deep register prefetch, 2 barriers/K-step (verified sync structure:
// compiler-tracked global_load/ds_write/ds_read only, no async DMA).
//  (a) NO XCD remap: mt = blockIdx&7 == XCD id under round-robin dispatch, so
//      each XCD's L2 dirties a disjoint 128-row output slice (R1: 1.8x vs 4.9x).
//  (b) nontemporal output stores: no write-allocate, no L2/L3 dirty churn ->
//      weight (102 MB bf16) stays L3-resident.
__global__ __launch_bounds__(256, 4)
void arc_gemm_fast(const unsigned short* __restrict__ xn,
                   const unsigned short* __restrict__ wn,
                   const int* __restrict__ tgt,
                   const float* __restrict__ diff,
                   float* __restrict__ out) {
    __shared__ unsigned short SMEM[2 * 128 * FS];   // As | Bs; reused as float[64][128]
    unsigned short* const As = SMEM;
    unsigned short* const Bs = SMEM + 128 * FS;

    const int t    = threadIdx.x;
    const int lane = t & 63;
    const int wid  = t >> 6;

    const int mt = blockIdx.x & 7;      // == XCD id under round-robin dispatch
    const int nt = blockIdx.x >> 3;
    const int m0 = mt * 128;
    const int n0 = nt * 128;
    const int wm = (wid & 1) * 64;
    const int wnc = (wid >> 1) * 64;

    // staging: 2 threads per row, 32 k-elems (4x uint4) each
    const int sr = t >> 1;
    const int sk = (t & 1) * 32;
    const unsigned short* Ag = xn + (size_t)(m0 + sr) * DDIM + sk;
    int brow = n0 + sr; brow = brow < CDIM ? brow : (CDIM - 1);   // tail clamp
    const unsigned short* Bg = wn + (size_t)brow * DDIM + sk;
    unsigned short* al = &As[sr * FS + sk];
    unsigned short* bl = &Bs[sr * FS + sk];

    f32x4 acc[4][4] = {};
    uint4 ar[2][4], br[2][4];           // two-tile-deep prefetch sets

#pragma unroll
    for (int s = 0; s < 2; ++s)         // prologue: tiles 0,1 -> reg sets 0,1
#pragma unroll
        for (int i = 0; i < 4; ++i) {
            ar[s][i] = *(const uint4*)(Ag + s * 64 + i * 8);
            br[s][i] = *(const uint4*)(Bg + s * 64 + i * 8);
        }

#pragma unroll
    for (int ks = 0; ks < 8; ++ks) {    // fully unrolled: ks&1 is static
        const int s = ks & 1;
#pragma unroll
        for (int i = 0; i < 4; ++i) {   // regs -> LDS (waits only set s's loads)
            *(uint4*)(al + i * 8) = ar[s][i];
            *(uint4*)(bl + i * 8) = br[s][i];
        }
        __syncthreads();                // writes visible to all waves
        if (ks + 2 < 8) {
#pragma unroll
            for (int i = 0; i < 4; ++i) {   // refill set s with tile ks+2
                ar[s][i] = *(const uint4*)(Ag + (ks + 2) * 64 + i * 8);
                br[s][i] = *(const uint4*)(Bg + (ks + 2) * 64 + i * 8);
            }
        }
#pragma unroll
        for (int hk = 0; hk < 2; ++hk) {
            bf16x8 av[4], bv[4];
            const int ko = hk * 32 + (lane >> 4) * 8;
#pragma unroll
            for (int f = 0; f < 4; ++f) {
                av[f] = *(const bf16x8*)(&As[(wm  + f * 16 + (lane & 15)) * FS + ko]);
                bv[f] = *(const bf16x8*)(&Bs[(wnc + f * 16 + (lane & 15)) * FS + ko]);
            }
#pragma unroll
            for (int mf = 0; mf < 4; ++mf)
#pragma unroll
                for (int nf = 0; nf < 4; ++nf)
                    acc[mf][nf] = __builtin_amdgcn_mfma_f32_16x16x32_bf16(
                        av[mf], bv[nf], acc[mf][nf], 0, 0, 0);
        }
        if (ks < 7) __syncthreads();    // all reads done before next overwrite
    }

    // ---- epilogue: 2 passes of 64 rows through LDS, nontemporal f32x4 stores ----
    float* const Cs = (float*)SMEM;     // [64][128] fp32 = 32 KB
#pragma unroll
    for (int p = 0; p < 2; ++p) {
        __syncthreads();                // LDS free (prev reads / prev store pass done)
        if ((wid & 1) == p) {           // waves holding rows [p*64, p*64+64)
#pragma unroll
            for (int mf = 0; mf < 4; ++mf)
#pragma unroll
                for (int j = 0; j < 4; ++j) {
                    const int lr = mf * 16 + (lane >> 4) * 4 + j;
#pragma unroll
                    for (int nf = 0; nf < 4; ++nf)
                        Cs[lr * 128 + wnc + nf * 16 + (lane & 15)] = acc[mf][nf][j];
                }
        }
        __syncthreads();
        // 256 threads: 8 rows/iter, 32 f32x4 per row (dense 512B row segments)
#pragma unroll
        for (int it = 0; it < 8; ++it) {
            const int r    = it * 8 + (t >> 5);     // 0..63
            const int c4   = (t & 31) * 4;          // col within tile
            const int grow = m0 + p * 64 + r;
            const int gc0  = n0 + c4;
            if (gc0 < CDIM) {
                f32x4 v = *(const f32x4*)&Cs[r * 128 + c4];
                const int   tg = tgt[grow];
                const float dv = diff[grow];
                if (gc0     == tg) v[0] += dv;
                if (gc0 + 1 == tg) v[1] += dv;
                if (gc0 + 2 == tg) v[2] += dv;
                if (gc0 + 3 == tg) v[3] += dv;
                v *= 64.0f;
                __builtin_nontemporal_store(v, (f32x4*)(out + (size_t)grow * CDIM + gc0));
            }
        }
    }
}

// =====================  FALLBACK PATH (round-1 structure, fp32 B)  =====================
__global__ __launch_bounds__(256, 2)
void arc_gemm_kernel(const unsigned short* __restrict__ xn,
                     const float* __restrict__ w,
                     const float* __restrict__ sw,
                     const int* __restrict__ tgt,
                     const float* __restrict__ diff,
                     float* __restrict__ out) {
    __shared__ unsigned short As[2][128 * FB_STRIDE];
    __shared__ unsigned short Bs[2][128 * FB_STRIDE];

    const int t    = threadIdx.x;
    const int lane = t & 63;
    const int wid  = t >> 6;
    const int mt   = blockIdx.x & 7;
    const int nt   = blockIdx.x >> 3;
    const int m0   = mt * 128;
    const int n0   = nt * 128;
    const int wm   = (wid & 1) * 64;
    const int wn   = (wid >> 1) * 64;

    const int sr = t >> 1;
    const int sk = (t & 1) * 32;

    const unsigned short* Ag = xn + (m0 + sr) * DDIM + sk;
    int brow = n0 + sr; brow = brow < CDIM ? brow : (CDIM - 1);
    const float* Bg = w + (size_t)brow * DDIM + sk;

    f32x4 acc[4][4] = {};
    uint4  ar[4];
    float4 br[8];

#define LOAD_TILE(kk) do {                                                     \
    _Pragma("unroll") for (int i = 0; i < 4; ++i)                              \
        ar[i] = *(const uint4*)(Ag + (kk) + i * 8);                            \
    _Pragma("unroll") for (int i = 0; i < 8; ++i)                              \
        br[i] = *(const float4*)(Bg + (kk) + i * 4);                           \
} while (0)

#define STORE_TILE(bufi) do {                                                  \
    unsigned short* ab = &As[bufi][sr * FB_STRIDE + sk];                       \
    unsigned short* bb = &Bs[bufi][sr * FB_STRIDE + sk];                       \
    _Pragma("unroll") for (int i = 0; i < 4; ++i)                              \
        *(uint4*)(ab + i * 8) = ar[i];                                         \
    _Pragma("unroll") for (int j = 0; j < 4; ++j)                              \
        *(uint4*)(bb + j * 8) = pack8(br[2 * j], br[2 * j + 1]);               \
} while (0)

#define MFMA_STEP(bufi) do {                                                   \
    _Pragma("unroll") for (int hk = 0; hk < 2; ++hk) {                         \
        bf16x8 av[4], bv[4];                                                   \
        const int ko = hk * 32 + (lane >> 4) * 8;                              \
        _Pragma("unroll") for (int f = 0; f < 4; ++f) {                        \
            av[f] = *(const bf16x8*)(&As[bufi][(wm + f * 16 + (lane & 15)) * FB_STRIDE + ko]); \
            bv[f] = *(const bf16x8*)(&Bs[bufi][(wn + f * 16 + (lane & 15)) * FB_STRIDE + ko]); \
        }                                                                      \
        _Pragma("unroll") for (int mf = 0; mf < 4; ++mf)                       \
            _Pragma("unroll") for (int nf = 0; nf < 4; ++nf)                   \
                acc[mf][nf] = __builtin_amdgcn_mfma_f32_16x16x32_bf16(         \
                    av[mf], bv[nf], acc[mf][nf], 0, 0, 0);                     \
    }                                                                          \
} while (0)

    LOAD_TILE(0);
    STORE_TILE(0);
#pragma unroll
    for (int ks = 0; ks < 8; ++ks) {
        const int cur = ks & 1;
        if (ks < 7) LOAD_TILE((ks + 1) * 64);
        __syncthreads();
        MFMA_STEP(cur);
        if (ks < 7) STORE_TILE(cur ^ 1);
    }

    float swv[4];
    int   gcv[4];
#pragma unroll
    for (int nf = 0; nf < 4; ++nf) {
        int gc = n0 + wn + nf * 16 + (lane & 15);
        gcv[nf] = gc;
        swv[nf] = sw[gc < CDIM ? gc : (CDIM - 1)];
    }
#pragma unroll
    for (int mf = 0; mf < 4; ++mf) {
#pragma unroll
        for (int j = 0; j < 4; ++j) {
            const int grow = m0 + wm + mf * 16 + (lane >> 4) * 4 + j;
            const int tg = tgt[grow];
            const float dv = diff[grow];
            float* orow = out + (size_t)grow * CDIM;
#pragma unroll
            for (int nf = 0; nf < 4; ++nf) {
                const int gc = gcv[nf];
                if (gc < CDIM) {
                    float v = acc[mf][nf][j] * swv[nf];
                    if (gc == tg) v += dv;
                    orow[gc] = v * 64.0f;
                }
            }
        }
    }
#undef LOAD_TILE
#undef STORE_TILE
#undef MFMA_STEP
}

extern "C" void kernel_launch(void* const* d_in, const int* in_sizes, int n_in,
                              void* d_out, int out_size, void* d_ws, size_t ws_size,
                              hipStream_t stream) {
    const float* x   = (const float*)d_in[0];
    const float* w   = (const float*)d_in[1];
    const int*   tgt = (const int*)d_in[2];
    float* out = (float*)d_out;

    unsigned short* xn = (unsigned short*)d_ws;                          // 1 MB
    const size_t xn_bytes   = (size_t)BDIM * DDIM * 2;
    float* diff = (float*)((char*)d_ws + xn_bytes);                      // 4 KB
    const size_t diff_bytes = (size_t)BDIM * 4;
    const size_t wn_bytes   = (size_t)CDIM * DDIM * 2;                   // 102.4 MB
    const int ntiles = (CDIM + 127) / 128;                               // 782

    hipLaunchKernelGGL(rownorm_bf16_kernel, dim3(BDIM / 4), dim3(256), 0, stream, x, xn);
    hipLaunchKernelGGL(tdiff_kernel, dim3(BDIM / 4), dim3(256), 0, stream, x, w, tgt, diff);

    if (ws_size >= xn_bytes + diff_bytes + wn_bytes) {
        // FAST: normalize+convert weight once, then all-bf16 reg-staged GEMM
        unsigned short* wnb = (unsigned short*)((char*)d_ws + xn_bytes + diff_bytes);
        hipLaunchKernelGGL(rownorm_bf16_kernel, dim3(CDIM / 4), dim3(256), 0, stream, w, wnb);
        hipLaunchKernelGGL(arc_gemm_fast, dim3(8 * ntiles), dim3(256), 0, stream,
                           xn, wnb, tgt, diff, out);
    } else {
        // FALLBACK: fp32 B, reg-staged, round-1-verified structure
        float* sw = (float*)((char*)d_ws + xn_bytes + diff_bytes);
        hipLaunchKernelGGL(wnorm_kernel, dim3(CDIM / 4), dim3(256), 0, stream, w, sw);
        hipLaunchKernelGGL(arc_gemm_kernel, dim3(8 * ntiles), dim3(256), 0, stream,
                           xn, w, sw, tgt, diff, out);
    }
}